// Round 1
// baseline (887.768 us; speedup 1.0000x reference)
//
#include <hip/hip_runtime.h>
#include <math.h>

// Problem constants
#define BB 4
#define TT 1024
#define EE 1024
#define HH 16
#define DD 64
#define MTOT (BB*TT)          // 4096 rows
#define KDIM 1024

// ---------------------------------------------------------------------------
// Shared 128x128x16 fp32 GEMM body: C = A @ W^T  (A[M,K] row-major, W[N,K]
// row-major, both K-contiguous). 256 threads, 8x8 acc per thread.
// LDS stored transposed As[k][m] with +4 pad (132) — A reads conflict-free,
// B reads 4-way (acceptable: FMA-bound, 64 FMA per 4 LDS b128 reads).
// ---------------------------------------------------------------------------
__device__ __forceinline__
void gemm128_body(const float* __restrict__ A, const float* __restrict__ W,
                  int mbase, int nbase, float acc[8][8])
{
    __shared__ float As[16][132];
    __shared__ float Bs[16][132];
    const int tid = threadIdx.x;
    const int tx = tid & 15;   // n dim, 8 cols each
    const int ty = tid >> 4;   // m dim, 8 rows each

#pragma unroll 1
    for (int kt = 0; kt < KDIM; kt += 16) {
        __syncthreads();
#pragma unroll
        for (int i = 0; i < 2; i++) {
            int f   = tid + i * 256;       // float4 id, 4 per row of 16 k
            int row = f >> 2;
            int kc  = (f & 3) << 2;
            float4 av = *(const float4*)(A + (size_t)(mbase + row) * KDIM + kt + kc);
            As[kc + 0][row] = av.x; As[kc + 1][row] = av.y;
            As[kc + 2][row] = av.z; As[kc + 3][row] = av.w;
            float4 bv = *(const float4*)(W + (size_t)(nbase + row) * KDIM + kt + kc);
            Bs[kc + 0][row] = bv.x; Bs[kc + 1][row] = bv.y;
            Bs[kc + 2][row] = bv.z; Bs[kc + 3][row] = bv.w;
        }
        __syncthreads();
#pragma unroll
        for (int kk = 0; kk < 16; kk++) {
            float4 a0 = *(const float4*)&As[kk][ty * 8];
            float4 a1 = *(const float4*)&As[kk][ty * 8 + 4];
            float4 b0 = *(const float4*)&Bs[kk][tx * 8];
            float4 b1 = *(const float4*)&Bs[kk][tx * 8 + 4];
            float am[8] = {a0.x, a0.y, a0.z, a0.w, a1.x, a1.y, a1.z, a1.w};
            float bn[8] = {b0.x, b0.y, b0.z, b0.w, b1.x, b1.y, b1.z, b1.w};
#pragma unroll
            for (int i = 0; i < 8; i++)
#pragma unroll
                for (int j = 0; j < 8; j++)
                    acc[i][j] = fmaf(am[i], bn[j], acc[i][j]);
        }
    }
}

// ---------------------------------------------------------------------------
// Fused QKV projection. gridDim.x = 24 (widx = x/8 selects q/k/v, 8 n-tiles),
// gridDim.y = 32 (m-tiles). Output scattered to [B,H,T,D]; q scaled by 1/8.
// ---------------------------------------------------------------------------
__global__ __launch_bounds__(256)
void qkv_kernel(const float* __restrict__ hs,
                const float* __restrict__ Wq, const float* __restrict__ Wk,
                const float* __restrict__ Wv,
                const float* __restrict__ bq, const float* __restrict__ bk,
                const float* __restrict__ bv,
                float* __restrict__ qb, float* __restrict__ kb,
                float* __restrict__ vb)
{
    const int widx  = blockIdx.x >> 3;
    const int nbase = (blockIdx.x & 7) * 128;
    const int mbase = blockIdx.y * 128;
    const float* W    = (widx == 0) ? Wq : (widx == 1) ? Wk : Wv;
    const float* bias = (widx == 0) ? bq : (widx == 1) ? bk : bv;
    float*       dst  = (widx == 0) ? qb : (widx == 1) ? kb : vb;
    const float scale = (widx == 0) ? 0.125f : 1.0f;   // D^-0.5 = 64^-0.5

    float acc[8][8] = {};
    gemm128_body(hs, W, mbase, nbase, acc);

    const int tx = threadIdx.x & 15;
    const int ty = threadIdx.x >> 4;
#pragma unroll
    for (int i = 0; i < 8; i++) {
        int m = mbase + ty * 8 + i;
        int b = m >> 10, t = m & 1023;
#pragma unroll
        for (int j4 = 0; j4 < 2; j4++) {
            int n0 = nbase + tx * 8 + j4 * 4;
            int h = n0 >> 6, d = n0 & 63;
            float4 bi = *(const float4*)(bias + n0);
            float4 o;
            o.x = (acc[i][j4 * 4 + 0] + bi.x) * scale;
            o.y = (acc[i][j4 * 4 + 1] + bi.y) * scale;
            o.z = (acc[i][j4 * 4 + 2] + bi.z) * scale;
            o.w = (acc[i][j4 * 4 + 3] + bi.w) * scale;
            *(float4*)(dst + (((size_t)(b * HH + h) * TT + t) * DD + d)) = o;
        }
    }
}

// ---------------------------------------------------------------------------
// Out projection: out = ctx @ Wo^T + bo, plain [M,N] row-major output.
// ---------------------------------------------------------------------------
__global__ __launch_bounds__(256)
void outproj_kernel(const float* __restrict__ ctx, const float* __restrict__ Wo,
                    const float* __restrict__ bo, float* __restrict__ out)
{
    const int nbase = blockIdx.x * 128;
    const int mbase = blockIdx.y * 128;
    float acc[8][8] = {};
    gemm128_body(ctx, Wo, mbase, nbase, acc);

    const int tx = threadIdx.x & 15;
    const int ty = threadIdx.x >> 4;
#pragma unroll
    for (int i = 0; i < 8; i++) {
        int m = mbase + ty * 8 + i;
#pragma unroll
        for (int j4 = 0; j4 < 2; j4++) {
            int n0 = nbase + tx * 8 + j4 * 4;
            float4 bi = *(const float4*)(bo + n0);
            float4 o;
            o.x = acc[i][j4 * 4 + 0] + bi.x;
            o.y = acc[i][j4 * 4 + 1] + bi.y;
            o.z = acc[i][j4 * 4 + 2] + bi.z;
            o.w = acc[i][j4 * 4 + 3] + bi.w;
            *(float4*)(out + (size_t)m * EE + n0) = o;
        }
    }
}

// ---------------------------------------------------------------------------
// Flash attention, fp32. One block per (q-tile of 64 rows, b*h).
// 256 threads: ty=tid/16 owns 4 rows (m), tx=tid%16 owns 4 cols (n or d).
// LDS tiles 64x64 with XOR swizzle (phys_c4 = c4 ^ (row>>2)) -> every LDS
// access <=2-way banked (free on gfx950, m136). LDS = 4*16KB = 64KB ->
// 2 blocks/CU.
// ---------------------------------------------------------------------------
__device__ __forceinline__ float4 lds_ld(const float* buf, int r, int c) {
    return *(const float4*)&buf[(r * 16 + (((c >> 2) ^ (r >> 2)) & 15)) * 4];
}
__device__ __forceinline__ void lds_st(float* buf, int r, int c, float4 v) {
    *(float4*)&buf[(r * 16 + (((c >> 2) ^ (r >> 2)) & 15)) * 4] = v;
}

__global__ __launch_bounds__(256)
void attn_kernel(const float* __restrict__ q, const float* __restrict__ k,
                 const float* __restrict__ v, const float* __restrict__ mask,
                 float* __restrict__ ctx)
{
    __shared__ float Qs[64 * 64];
    __shared__ float Ks[64 * 64];
    __shared__ float Vs[64 * 64];
    __shared__ float Ps[64 * 64];

    const int bh = blockIdx.y;            // b*16 + h
    const int b  = bh >> 4;
    const int h  = bh & 15;
    const int m0 = blockIdx.x * 64;
    const float* qh = q + (size_t)bh * TT * DD;
    const float* kh = k + (size_t)bh * TT * DD;
    const float* vh = v + (size_t)bh * TT * DD;
    const float* mb = mask + (size_t)b * TT * TT;

    const int tid = threadIdx.x;
    const int tx  = tid & 15;
    const int ty  = tid >> 4;

    // stage Q tile (64x64 = 1024 float4, 4 per thread)
#pragma unroll
    for (int i = 0; i < 4; i++) {
        int f = tid + i * 256;
        int row = f >> 4, c = (f & 15) << 2;
        lds_st(Qs, row, c, *(const float4*)(qh + (size_t)(m0 + row) * DD + c));
    }

    float m_i[4], l_i[4], o[4][4];
#pragma unroll
    for (int i = 0; i < 4; i++) {
        m_i[i] = -INFINITY; l_i[i] = 0.f;
#pragma unroll
        for (int j = 0; j < 4; j++) o[i][j] = 0.f;
    }

    for (int n0 = 0; n0 < TT; n0 += 64) {
        __syncthreads();   // protect Ks/Vs/Ps from previous iteration readers
#pragma unroll
        for (int i = 0; i < 4; i++) {
            int f = tid + i * 256;
            int row = f >> 4, c = (f & 15) << 2;
            lds_st(Ks, row, c, *(const float4*)(kh + (size_t)(n0 + row) * DD + c));
            lds_st(Vs, row, c, *(const float4*)(vh + (size_t)(n0 + row) * DD + c));
        }
        __syncthreads();

        // S = Q . K^T + mask   (s[i][j]: row m0+ty*4+i, col n0+tx*4+j)
        float s[4][4];
#pragma unroll
        for (int i = 0; i < 4; i++) {
            float4 mv = *(const float4*)(mb + (size_t)(m0 + ty * 4 + i) * TT + n0 + tx * 4);
            s[i][0] = mv.x; s[i][1] = mv.y; s[i][2] = mv.z; s[i][3] = mv.w;
        }
#pragma unroll
        for (int dk = 0; dk < 64; dk += 4) {
            float4 qv[4], kv[4];
#pragma unroll
            for (int i = 0; i < 4; i++) qv[i] = lds_ld(Qs, ty * 4 + i, dk);
#pragma unroll
            for (int j = 0; j < 4; j++) kv[j] = lds_ld(Ks, tx * 4 + j, dk);
#pragma unroll
            for (int i = 0; i < 4; i++)
#pragma unroll
                for (int j = 0; j < 4; j++) {
                    s[i][j] = fmaf(qv[i].x, kv[j].x, s[i][j]);
                    s[i][j] = fmaf(qv[i].y, kv[j].y, s[i][j]);
                    s[i][j] = fmaf(qv[i].z, kv[j].z, s[i][j]);
                    s[i][j] = fmaf(qv[i].w, kv[j].w, s[i][j]);
                }
        }

        // online softmax (rows owned by the 16 lanes sharing ty)
#pragma unroll
        for (int i = 0; i < 4; i++) {
            float rmax = fmaxf(fmaxf(s[i][0], s[i][1]), fmaxf(s[i][2], s[i][3]));
#pragma unroll
            for (int w = 1; w < 16; w <<= 1)
                rmax = fmaxf(rmax, __shfl_xor(rmax, w, 64));
            float mnew  = fmaxf(m_i[i], rmax);
            float alpha = __expf(m_i[i] - mnew);   // exp(-inf)=0 first pass
            float rsum = 0.f;
#pragma unroll
            for (int j = 0; j < 4; j++) { s[i][j] = __expf(s[i][j] - mnew); rsum += s[i][j]; }
#pragma unroll
            for (int w = 1; w < 16; w <<= 1)
                rsum += __shfl_xor(rsum, w, 64);
            l_i[i] = l_i[i] * alpha + rsum;
            m_i[i] = mnew;
#pragma unroll
            for (int j = 0; j < 4; j++) o[i][j] *= alpha;
            lds_st(Ps, ty * 4 + i, tx * 4, make_float4(s[i][0], s[i][1], s[i][2], s[i][3]));
        }
        __syncthreads();

        // O += P . V   (o[i][j]: row m0+ty*4+i, d = tx*4+j)
#pragma unroll
        for (int nn = 0; nn < 64; nn += 4) {
            float4 pv[4], vv[4];
#pragma unroll
            for (int i = 0; i < 4; i++) pv[i] = lds_ld(Ps, ty * 4 + i, nn);
#pragma unroll
            for (int r = 0; r < 4; r++) vv[r] = lds_ld(Vs, nn + r, tx * 4);
#pragma unroll
            for (int i = 0; i < 4; i++) {
                o[i][0] = fmaf(pv[i].x, vv[0].x, o[i][0]);
                o[i][0] = fmaf(pv[i].y, vv[1].x, o[i][0]);
                o[i][0] = fmaf(pv[i].z, vv[2].x, o[i][0]);
                o[i][0] = fmaf(pv[i].w, vv[3].x, o[i][0]);
                o[i][1] = fmaf(pv[i].x, vv[0].y, o[i][1]);
                o[i][1] = fmaf(pv[i].y, vv[1].y, o[i][1]);
                o[i][1] = fmaf(pv[i].z, vv[2].y, o[i][1]);
                o[i][1] = fmaf(pv[i].w, vv[3].y, o[i][1]);
                o[i][2] = fmaf(pv[i].x, vv[0].z, o[i][2]);
                o[i][2] = fmaf(pv[i].y, vv[1].z, o[i][2]);
                o[i][2] = fmaf(pv[i].z, vv[2].z, o[i][2]);
                o[i][2] = fmaf(pv[i].w, vv[3].z, o[i][2]);
                o[i][3] = fmaf(pv[i].x, vv[0].w, o[i][3]);
                o[i][3] = fmaf(pv[i].y, vv[1].w, o[i][3]);
                o[i][3] = fmaf(pv[i].z, vv[2].w, o[i][3]);
                o[i][3] = fmaf(pv[i].w, vv[3].w, o[i][3]);
            }
        }
    }

    // epilogue: normalize and write ctx as [B,T,E] (E index = h*64 + d)
#pragma unroll
    for (int i = 0; i < 4; i++) {
        float inv = 1.0f / l_i[i];
        int m = m0 + ty * 4 + i;
        float4 ov = make_float4(o[i][0] * inv, o[i][1] * inv, o[i][2] * inv, o[i][3] * inv);
        *(float4*)(ctx + ((size_t)(b * TT + m) * EE) + h * DD + tx * 4) = ov;
    }
}

// ---------------------------------------------------------------------------
extern "C" void kernel_launch(void* const* d_in, const int* in_sizes, int n_in,
                              void* d_out, int out_size, void* d_ws, size_t ws_size,
                              hipStream_t stream)
{
    const float* hs   = (const float*)d_in[0];
    const float* mask = (const float*)d_in[1];
    const float* Wq   = (const float*)d_in[2];
    const float* bq   = (const float*)d_in[3];
    const float* Wk   = (const float*)d_in[4];
    const float* bk   = (const float*)d_in[5];
    const float* Wv   = (const float*)d_in[6];
    const float* bv   = (const float*)d_in[7];
    const float* Wo   = (const float*)d_in[8];
    const float* bo   = (const float*)d_in[9];
    float* out = (float*)d_out;

    const size_t NQKV = (size_t)BB * HH * TT * DD;   // 4.19M elems each
    float* qb  = (float*)d_ws;
    float* kb  = qb + NQKV;
    float* vb  = kb + NQKV;
    float* ctx = vb + NQKV;                          // [B,T,E]

    qkv_kernel<<<dim3(24, 32), 256, 0, stream>>>(hs, Wq, Wk, Wv, bq, bk, bv, qb, kb, vb);
    attn_kernel<<<dim3(TT / 64, BB * HH), 256, 0, stream>>>(qb, kb, vb, mask, ctx);
    outproj_kernel<<<dim3(8, 32), 256, 0, stream>>>(ctx, Wo, bo, out);
}

// Round 2
// 613.836 us; speedup vs baseline: 1.4463x; 1.4463x over previous
//
#include <hip/hip_runtime.h>
#include <math.h>

// Problem constants
#define BB 4
#define TT 1024
#define EE 1024
#define HH 16
#define DD 64
#define KDIM 1024

typedef short bf16x8 __attribute__((ext_vector_type(8)));   // 8 bf16 raw bits (4 VGPRs)
typedef float f32x4  __attribute__((ext_vector_type(4)));

// round-to-nearest-even fp32 -> bf16 bits
__device__ __forceinline__ unsigned short f2bf(float x) {
    unsigned int u = __builtin_bit_cast(unsigned int, x);
    u += 0x7FFFu + ((u >> 16) & 1u);
    return (unsigned short)(u >> 16);
}
// split x = hi + lo (both bf16, RTNE)
__device__ __forceinline__ void split_bf(float x, unsigned short& hi, unsigned short& lo) {
    unsigned int u  = __builtin_bit_cast(unsigned int, x);
    unsigned int uh = u + 0x7FFFu + ((u >> 16) & 1u);
    hi = (unsigned short)(uh >> 16);
    float hf = __builtin_bit_cast(float, uh & 0xFFFF0000u);
    lo = f2bf(x - hf);
}

// ---------------------------------------------------------------------------
// fp32 128x128x16 GEMM body (unchanged from R1): C = A @ W^T.
// ---------------------------------------------------------------------------
__device__ __forceinline__
void gemm128_body(const float* __restrict__ A, const float* __restrict__ W,
                  int mbase, int nbase, float acc[8][8])
{
    __shared__ float As[16][132];
    __shared__ float Bs[16][132];
    const int tid = threadIdx.x;
    const int tx = tid & 15;
    const int ty = tid >> 4;

#pragma unroll 1
    for (int kt = 0; kt < KDIM; kt += 16) {
        __syncthreads();
#pragma unroll
        for (int i = 0; i < 2; i++) {
            int f   = tid + i * 256;
            int row = f >> 2;
            int kc  = (f & 3) << 2;
            float4 av = *(const float4*)(A + (size_t)(mbase + row) * KDIM + kt + kc);
            As[kc + 0][row] = av.x; As[kc + 1][row] = av.y;
            As[kc + 2][row] = av.z; As[kc + 3][row] = av.w;
            float4 bv = *(const float4*)(W + (size_t)(nbase + row) * KDIM + kt + kc);
            Bs[kc + 0][row] = bv.x; Bs[kc + 1][row] = bv.y;
            Bs[kc + 2][row] = bv.z; Bs[kc + 3][row] = bv.w;
        }
        __syncthreads();
#pragma unroll
        for (int kk = 0; kk < 16; kk++) {
            float4 a0 = *(const float4*)&As[kk][ty * 8];
            float4 a1 = *(const float4*)&As[kk][ty * 8 + 4];
            float4 b0 = *(const float4*)&Bs[kk][tx * 8];
            float4 b1 = *(const float4*)&Bs[kk][tx * 8 + 4];
            float am[8] = {a0.x, a0.y, a0.z, a0.w, a1.x, a1.y, a1.z, a1.w};
            float bn[8] = {b0.x, b0.y, b0.z, b0.w, b1.x, b1.y, b1.z, b1.w};
#pragma unroll
            for (int i = 0; i < 8; i++)
#pragma unroll
                for (int j = 0; j < 8; j++)
                    acc[i][j] = fmaf(am[i], bn[j], acc[i][j]);
        }
    }
}

// ---------------------------------------------------------------------------
// Fused QKV projection -> bf16 hi/lo planes in [B,H,T,D] layout, q pre-scaled.
// ---------------------------------------------------------------------------
__global__ __launch_bounds__(256)
void qkv_kernel(const float* __restrict__ hs,
                const float* __restrict__ Wq, const float* __restrict__ Wk,
                const float* __restrict__ Wv,
                const float* __restrict__ bq, const float* __restrict__ bk,
                const float* __restrict__ bv,
                unsigned short* __restrict__ qhi, unsigned short* __restrict__ qlo,
                unsigned short* __restrict__ khi, unsigned short* __restrict__ klo,
                unsigned short* __restrict__ vhi, unsigned short* __restrict__ vlo)
{
    const int widx  = blockIdx.x >> 3;
    const int nbase = (blockIdx.x & 7) * 128;
    const int mbase = blockIdx.y * 128;
    const float* W    = (widx == 0) ? Wq : (widx == 1) ? Wk : Wv;
    const float* bias = (widx == 0) ? bq : (widx == 1) ? bk : bv;
    unsigned short* dhi = (widx == 0) ? qhi : (widx == 1) ? khi : vhi;
    unsigned short* dlo = (widx == 0) ? qlo : (widx == 1) ? klo : vlo;
    const float scale = (widx == 0) ? 0.125f : 1.0f;   // D^-0.5

    float acc[8][8] = {};
    gemm128_body(hs, W, mbase, nbase, acc);

    const int tx = threadIdx.x & 15;
    const int ty = threadIdx.x >> 4;
#pragma unroll
    for (int i = 0; i < 8; i++) {
        int m = mbase + ty * 8 + i;
        int b = m >> 10, t = m & 1023;
#pragma unroll
        for (int j4 = 0; j4 < 2; j4++) {
            int n0 = nbase + tx * 8 + j4 * 4;
            int h = n0 >> 6, d = n0 & 63;
            float4 bi = *(const float4*)(bias + n0);
            float vals[4];
            vals[0] = (acc[i][j4 * 4 + 0] + bi.x) * scale;
            vals[1] = (acc[i][j4 * 4 + 1] + bi.y) * scale;
            vals[2] = (acc[i][j4 * 4 + 2] + bi.z) * scale;
            vals[3] = (acc[i][j4 * 4 + 3] + bi.w) * scale;
            ushort4 hi4, lo4;
            split_bf(vals[0], hi4.x, lo4.x);
            split_bf(vals[1], hi4.y, lo4.y);
            split_bf(vals[2], hi4.z, lo4.z);
            split_bf(vals[3], hi4.w, lo4.w);
            size_t base = (((size_t)(b * HH + h) * TT + t) * DD + d);
            *(ushort4*)(dhi + base) = hi4;
            *(ushort4*)(dlo + base) = lo4;
        }
    }
}

// ---------------------------------------------------------------------------
// Out projection (fp32, unchanged)
// ---------------------------------------------------------------------------
__global__ __launch_bounds__(256)
void outproj_kernel(const float* __restrict__ ctx, const float* __restrict__ Wo,
                    const float* __restrict__ bo, float* __restrict__ out)
{
    const int nbase = blockIdx.x * 128;
    const int mbase = blockIdx.y * 128;
    float acc[8][8] = {};
    gemm128_body(ctx, Wo, mbase, nbase, acc);

    const int tx = threadIdx.x & 15;
    const int ty = threadIdx.x >> 4;
#pragma unroll
    for (int i = 0; i < 8; i++) {
        int m = mbase + ty * 8 + i;
#pragma unroll
        for (int j4 = 0; j4 < 2; j4++) {
            int n0 = nbase + tx * 8 + j4 * 4;
            float4 bi = *(const float4*)(bo + n0);
            float4 o;
            o.x = acc[i][j4 * 4 + 0] + bi.x;
            o.y = acc[i][j4 * 4 + 1] + bi.y;
            o.z = acc[i][j4 * 4 + 2] + bi.z;
            o.w = acc[i][j4 * 4 + 3] + bi.w;
            *(float4*)(out + (size_t)m * EE + n0) = o;
        }
    }
}

// ---------------------------------------------------------------------------
// MFMA flash attention. Block = 256 thr = 4 waves; BM=64 (16 q-rows/wave),
// BN=64, D=64. S = QK^T via split-bf16 (3 MFMAs), fp32 online softmax on
// C-frags, P->LDS(bf16)->A-frag, PV single-bf16 MFMA. LDS row stride 72
// (16B-aligned, <=2-way banks). LDS total 36.9 KB -> 4 blocks/CU.
// Layouts (verified, guide §3/m120): A-frag A[m=lane&15][k=quad*8+j],
// B-frag B[k=quad*8+j][n=lane&15], C/D col=lane&15 row=quad*4+reg.
// ---------------------------------------------------------------------------
#define LS 72   // LDS row stride in ushorts

__global__ __launch_bounds__(256)
void attn_kernel(const unsigned short* __restrict__ qh_, const unsigned short* __restrict__ ql_,
                 const unsigned short* __restrict__ kh_, const unsigned short* __restrict__ kl_,
                 const unsigned short* __restrict__ vh_,
                 const float* __restrict__ mask, float* __restrict__ ctx)
{
    __shared__ unsigned short Ksh[64 * LS];
    __shared__ unsigned short Ksl[64 * LS];
    __shared__ unsigned short Vt [64 * LS];
    __shared__ unsigned short Ps [64 * LS];

    const int bh = blockIdx.y;
    const int b  = bh >> 4;
    const int h  = bh & 15;
    const int m0 = blockIdx.x * 64;
    const size_t hoff = (size_t)bh * TT * DD;
    const unsigned short* qhp = qh_ + hoff;
    const unsigned short* qlp = ql_ + hoff;
    const unsigned short* khp = kh_ + hoff;
    const unsigned short* klp = kl_ + hoff;
    const unsigned short* vhp = vh_ + hoff;
    const float* mb = mask + (size_t)b * TT * TT;

    const int tid  = threadIdx.x;
    const int w    = tid >> 6;      // wave 0..3
    const int lane = tid & 63;
    const int quad = lane >> 4;
    const int l16  = lane & 15;

    // Q fragments, resident whole kernel (a-frag: m=l16, k=s*32+quad*8+j)
    bf16x8 qfh[2], qfl[2];
#pragma unroll
    for (int s = 0; s < 2; s++) {
        size_t off = (size_t)(m0 + w * 16 + l16) * DD + s * 32 + quad * 8;
        qfh[s] = *(const bf16x8*)(qhp + off);
        qfl[s] = *(const bf16x8*)(qlp + off);
    }

    f32x4 o[4];
    float m_i[4], l_i[4];
#pragma unroll
    for (int t = 0; t < 4; t++) o[t] = (f32x4)0.f;
#pragma unroll
    for (int r = 0; r < 4; r++) { m_i[r] = -INFINITY; l_i[r] = 0.f; }

    for (int n0 = 0; n0 < TT; n0 += 64) {
        // mask values for this tile (row m0+w*16+quad*4+r, col n0+16t+l16)
        float mreg[4][4];
#pragma unroll
        for (int t = 0; t < 4; t++)
#pragma unroll
            for (int r = 0; r < 4; r++)
                mreg[t][r] = mb[(size_t)(m0 + w * 16 + quad * 4 + r) * TT + n0 + 16 * t + l16];

        __syncthreads();   // previous iteration's readers done with Ks/Vt
        // stage K hi/lo tile: 512 x 16B units, rows of 64 ushorts -> stride LS
#pragma unroll
        for (int i = 0; i < 2; i++) {
            int u = tid + i * 256;
            int r = u >> 3, c8 = (u & 7) * 8;
            *(uint4*)&Ksh[r * LS + c8] = *(const uint4*)(khp + (size_t)(n0 + r) * DD + c8);
            *(uint4*)&Ksl[r * LS + c8] = *(const uint4*)(klp + (size_t)(n0 + r) * DD + c8);
        }
        // stage V transposed: lane n-fast (conflict-free 2B scatter)
        {
            int n  = tid & 63;
            int d0 = (tid >> 6) * 8;
#pragma unroll
            for (int half = 0; half < 2; half++) {
                int dd = d0 + half * 32;
                uint4 rv = *(const uint4*)(vhp + (size_t)(n0 + n) * DD + dd);
                unsigned int uu[4] = {rv.x, rv.y, rv.z, rv.w};
#pragma unroll
                for (int j = 0; j < 4; j++) {
                    Vt[(dd + 2 * j + 0) * LS + n] = (unsigned short)(uu[j] & 0xFFFFu);
                    Vt[(dd + 2 * j + 1) * LS + n] = (unsigned short)(uu[j] >> 16);
                }
            }
        }
        __syncthreads();

        // S = Q.K^T + mask (split-bf16: hi*hi + hi*lo + lo*hi)
        f32x4 st[4];
#pragma unroll
        for (int t = 0; t < 4; t++) {
            f32x4 sv;
            sv[0] = mreg[t][0]; sv[1] = mreg[t][1]; sv[2] = mreg[t][2]; sv[3] = mreg[t][3];
            st[t] = sv;
        }
#pragma unroll
        for (int s = 0; s < 2; s++) {
#pragma unroll
            for (int t = 0; t < 4; t++) {
                const bf16x8 kh = *(const bf16x8*)&Ksh[(16 * t + l16) * LS + s * 32 + quad * 8];
                const bf16x8 kl = *(const bf16x8*)&Ksl[(16 * t + l16) * LS + s * 32 + quad * 8];
                st[t] = __builtin_amdgcn_mfma_f32_16x16x32_bf16(qfh[s], kh, st[t], 0, 0, 0);
                st[t] = __builtin_amdgcn_mfma_f32_16x16x32_bf16(qfh[s], kl, st[t], 0, 0, 0);
                st[t] = __builtin_amdgcn_mfma_f32_16x16x32_bf16(qfl[s], kh, st[t], 0, 0, 0);
            }
        }

        // online softmax (fp32). Row r lives in component r, cols across 16 lanes x 4 t.
        float rm[4], rs[4], alpha[4];
#pragma unroll
        for (int r = 0; r < 4; r++)
            rm[r] = fmaxf(fmaxf(st[0][r], st[1][r]), fmaxf(st[2][r], st[3][r]));
#pragma unroll
        for (int mky = 1; mky < 16; mky <<= 1)
#pragma unroll
            for (int r = 0; r < 4; r++)
                rm[r] = fmaxf(rm[r], __shfl_xor(rm[r], mky));
#pragma unroll
        for (int r = 0; r < 4; r++) {
            float mn = fmaxf(m_i[r], rm[r]);
            alpha[r] = __expf(m_i[r] - mn);   // exp(-inf)=0 on first tile
            m_i[r]   = mn;
            rs[r]    = 0.f;
        }
#pragma unroll
        for (int t = 0; t < 4; t++)
#pragma unroll
            for (int r = 0; r < 4; r++) {
                float p = __expf(st[t][r] - m_i[r]);
                st[t][r] = p;
                rs[r] += p;
            }
#pragma unroll
        for (int mky = 1; mky < 16; mky <<= 1)
#pragma unroll
            for (int r = 0; r < 4; r++)
                rs[r] += __shfl_xor(rs[r], mky);
#pragma unroll
        for (int r = 0; r < 4; r++)
            l_i[r] = l_i[r] * alpha[r] + rs[r];
#pragma unroll
        for (int t = 0; t < 4; t++)
#pragma unroll
            for (int r = 0; r < 4; r++)
                o[t][r] *= alpha[r];

        // P (C-layout) -> LDS bf16, per-wave private 16-row strip
#pragma unroll
        for (int t = 0; t < 4; t++)
#pragma unroll
            for (int r = 0; r < 4; r++)
                Ps[(w * 16 + quad * 4 + r) * LS + 16 * t + l16] = f2bf(st[t][r]);
        // (same-wave LDS write->read: hardware in-order via lgkmcnt; no barrier needed)

        // O += P.V  (a-frag from Ps, b-frag from Vt)
#pragma unroll
        for (int s = 0; s < 2; s++) {
            const bf16x8 pf = *(const bf16x8*)&Ps[(w * 16 + l16) * LS + s * 32 + quad * 8];
#pragma unroll
            for (int t = 0; t < 4; t++) {
                const bf16x8 vf = *(const bf16x8*)&Vt[(16 * t + l16) * LS + s * 32 + quad * 8];
                o[t] = __builtin_amdgcn_mfma_f32_16x16x32_bf16(pf, vf, o[t], 0, 0, 0);
            }
        }
    }

    // epilogue: normalize, write ctx [B,T,E] fp32 (row=quad*4+r, d=16t+l16)
#pragma unroll
    for (int r = 0; r < 4; r++) {
        float inv = 1.0f / l_i[r];
        int m = m0 + w * 16 + quad * 4 + r;
#pragma unroll
        for (int t = 0; t < 4; t++)
            ctx[(size_t)(b * TT + m) * EE + h * DD + 16 * t + l16] = o[t][r] * inv;
    }
}

// ---------------------------------------------------------------------------
extern "C" void kernel_launch(void* const* d_in, const int* in_sizes, int n_in,
                              void* d_out, int out_size, void* d_ws, size_t ws_size,
                              hipStream_t stream)
{
    const float* hs   = (const float*)d_in[0];
    const float* mask = (const float*)d_in[1];
    const float* Wq   = (const float*)d_in[2];
    const float* bq   = (const float*)d_in[3];
    const float* Wk   = (const float*)d_in[4];
    const float* bk   = (const float*)d_in[5];
    const float* Wv   = (const float*)d_in[6];
    const float* bv   = (const float*)d_in[7];
    const float* Wo   = (const float*)d_in[8];
    const float* bo   = (const float*)d_in[9];
    float* out = (float*)d_out;

    const size_t NQKV = (size_t)BB * HH * TT * DD;   // 4.19M elems per plane
    unsigned short* qhi = (unsigned short*)d_ws;
    unsigned short* qlo = qhi + NQKV;
    unsigned short* khi = qlo + NQKV;
    unsigned short* klo = khi + NQKV;
    unsigned short* vhi = klo + NQKV;
    unsigned short* vlo = vhi + NQKV;
    float* ctx = (float*)(vlo + NQKV);               // [B,T,E] fp32

    qkv_kernel<<<dim3(24, 32), 256, 0, stream>>>(hs, Wq, Wk, Wv, bq, bk, bv,
                                                 qhi, qlo, khi, klo, vhi, vlo);
    attn_kernel<<<dim3(TT / 64, BB * HH), 256, 0, stream>>>(qhi, qlo, khi, klo, vhi, mask, ctx);
    outproj_kernel<<<dim3(8, 32), 256, 0, stream>>>(ctx, Wo, bo, out);
}

// Round 3
// 326.862 us; speedup vs baseline: 2.7160x; 1.8780x over previous
//
#include <hip/hip_runtime.h>
#include <math.h>

// Problem constants
#define BB 4
#define TT 1024
#define EE 1024
#define HH 16
#define DD 64
#define KDIM 1024
#define N_HS (4096 * 1024)     // hidden_states elems (also ctx)
#define N_W  (1024 * 1024)     // one weight matrix elems
#define NQKV (BB * HH * TT * DD)

typedef short bf16x8 __attribute__((ext_vector_type(8)));   // 8 bf16 raw bits
typedef float f32x4  __attribute__((ext_vector_type(4)));

// round-to-nearest-even fp32 -> bf16 bits
__device__ __forceinline__ unsigned short f2bf(float x) {
    unsigned int u = __builtin_bit_cast(unsigned int, x);
    u += 0x7FFFu + ((u >> 16) & 1u);
    return (unsigned short)(u >> 16);
}
// split x = hi + lo (both bf16, RTNE)
__device__ __forceinline__ void split_bf(float x, unsigned short& hi, unsigned short& lo) {
    unsigned int u  = __builtin_bit_cast(unsigned int, x);
    unsigned int uh = u + 0x7FFFu + ((u >> 16) & 1u);
    hi = (unsigned short)(uh >> 16);
    float hf = __builtin_bit_cast(float, uh & 0xFFFF0000u);
    lo = f2bf(x - hf);
}

// async global->LDS 16B copy
__device__ __forceinline__ void gload16(const void* g, void* l) {
    __builtin_amdgcn_global_load_lds(
        (const __attribute__((address_space(1))) void*)g,
        (__attribute__((address_space(3))) void*)l, 16, 0, 0);
}

// ---------------------------------------------------------------------------
// Elementwise fp32 -> bf16 hi/lo split for hs + 4 weights.
// ws layout (ushort units):
//   [0]            hs_hi (N_HS), hs_lo             (later aliased as ctx planes)
//   [2*N_HS]       wq_hi, wq_lo, wk_hi, wk_lo, wv_hi, wv_lo, wo_hi, wo_lo (N_W each)
//   [2*N_HS+8*N_W] q_hi, q_lo, k_hi, k_lo, v_hi    (NQKV each)
// ---------------------------------------------------------------------------
__global__ __launch_bounds__(256)
void split_kernel(const float* __restrict__ hs,
                  const float* __restrict__ Wq, const float* __restrict__ Wk,
                  const float* __restrict__ Wv, const float* __restrict__ Wo,
                  unsigned short* __restrict__ ws)
{
    const int u = blockIdx.x * 256 + threadIdx.x;   // float4 id, 2,097,152 total
    const float* src;
    unsigned short *dhi, *dlo;
    if (u < (N_HS / 4)) {
        src = hs + (size_t)u * 4;
        dhi = ws + (size_t)u * 4;
        dlo = dhi + N_HS;
    } else {
        int v = u - N_HS / 4;
        int wsel = v >> 18;             // N_W/4 = 262144 float4 per weight
        int wo   = v & 0x3FFFF;
        const float* Wsrc = (wsel == 0) ? Wq : (wsel == 1) ? Wk : (wsel == 2) ? Wv : Wo;
        src = Wsrc + (size_t)wo * 4;
        dhi = ws + 2 * (size_t)N_HS + (size_t)wsel * 2 * N_W + (size_t)wo * 4;
        dlo = dhi + N_W;
    }
    float4 x = *(const float4*)src;
    ushort4 hi4, lo4;
    split_bf(x.x, hi4.x, lo4.x);
    split_bf(x.y, hi4.y, lo4.y);
    split_bf(x.z, hi4.z, lo4.z);
    split_bf(x.w, hi4.w, lo4.w);
    *(ushort4*)dhi = hi4;
    *(ushort4*)dlo = lo4;
}

// ---------------------------------------------------------------------------
// Split-bf16 MFMA GEMM body: C = A @ W^T, A[M,K] and W[N,K] as bf16 hi/lo
// planes. 128x128 tile, BK=32, 4 waves (2x2 of 64x64), 16x16x32 MFMA,
// 3-term split (hh + hl + lh). global_load_lds width-16 staging into linear
// LDS with K-chunk XOR swizzle: chunk q of row r lives at slot
// r*4 + (q ^ ((r>>1)&3)) -> frag ds_read_b128 exactly 2-way banked (free).
// LDS = 4 x 8 KB = 32 KB.
// ---------------------------------------------------------------------------
__device__ __forceinline__
void mfma_gemm_body(const unsigned short* __restrict__ Ahg, const unsigned short* __restrict__ Alg,
                    const unsigned short* __restrict__ Bhg, const unsigned short* __restrict__ Blg,
                    int mbase, int nbase, f32x4 acc[4][4])
{
    __shared__ unsigned short Ah[128 * 32], Al[128 * 32];
    __shared__ unsigned short Bh[128 * 32], Bl[128 * 32];
    const int tid  = threadIdx.x;
    const int w    = tid >> 6;
    const int lane = tid & 63;
    const int quad = lane >> 4;
    const int l16  = lane & 15;
    const int wm   = (w >> 1) * 64;
    const int wn   = (w & 1) * 64;

#pragma unroll 1
    for (int kt = 0; kt < KDIM; kt += 32) {
        __syncthreads();   // previous iteration's readers done
#pragma unroll
        for (int i = 0; i < 2; i++) {
            int u = tid + i * 256;              // 16B chunk id, 512/plane
            int r = u >> 2, c = u & 3;
            int q = c ^ ((r >> 1) & 3);
            size_t ga = (size_t)(mbase + r) * KDIM + kt + q * 8;
            size_t gb = (size_t)(nbase + r) * KDIM + kt + q * 8;
            gload16(Ahg + ga, &Ah[u * 8]);
            gload16(Alg + ga, &Al[u * 8]);
            gload16(Bhg + gb, &Bh[u * 8]);
            gload16(Blg + gb, &Bl[u * 8]);
        }
        __syncthreads();   // vmcnt(0) drain + visibility

        bf16x8 af[4][2], bfr[4][2];
#pragma unroll
        for (int i = 0; i < 4; i++) {
            int r = wm + i * 16 + l16;
            int slot = r * 4 + (quad ^ ((r >> 1) & 3));
            af[i][0] = *(const bf16x8*)&Ah[slot * 8];
            af[i][1] = *(const bf16x8*)&Al[slot * 8];
        }
#pragma unroll
        for (int j = 0; j < 4; j++) {
            int r = wn + j * 16 + l16;
            int slot = r * 4 + (quad ^ ((r >> 1) & 3));
            bfr[j][0] = *(const bf16x8*)&Bh[slot * 8];
            bfr[j][1] = *(const bf16x8*)&Bl[slot * 8];
        }
#pragma unroll
        for (int i = 0; i < 4; i++)
#pragma unroll
            for (int j = 0; j < 4; j++) {
                acc[i][j] = __builtin_amdgcn_mfma_f32_16x16x32_bf16(af[i][0], bfr[j][0], acc[i][j], 0, 0, 0);
                acc[i][j] = __builtin_amdgcn_mfma_f32_16x16x32_bf16(af[i][0], bfr[j][1], acc[i][j], 0, 0, 0);
                acc[i][j] = __builtin_amdgcn_mfma_f32_16x16x32_bf16(af[i][1], bfr[j][0], acc[i][j], 0, 0, 0);
            }
    }
}

// ---------------------------------------------------------------------------
// QKV projection (MFMA). grid.x = 24: widx = x>>3 selects q/k/v, 8 n-tiles.
// Outputs bf16 hi/lo planes in [B,H,T,D]; q pre-scaled; v has hi plane only.
// ---------------------------------------------------------------------------
__global__ __launch_bounds__(256)
void qkv_kernel(const unsigned short* __restrict__ ws_ro,
                const float* __restrict__ bq, const float* __restrict__ bk,
                const float* __restrict__ bv,
                unsigned short* __restrict__ ws)
{
    const int widx  = blockIdx.x >> 3;
    const int nbase = (blockIdx.x & 7) * 128;
    const int mbase = blockIdx.y * 128;

    const unsigned short* hs_hi = ws_ro;
    const unsigned short* hs_lo = ws_ro + N_HS;
    const unsigned short* Wh = ws_ro + 2 * (size_t)N_HS + (size_t)widx * 2 * N_W;
    const unsigned short* Wl = Wh + N_W;
    const float* bias = (widx == 0) ? bq : (widx == 1) ? bk : bv;
    unsigned short* qkvb = ws + 2 * (size_t)N_HS + 8 * (size_t)N_W;
    unsigned short* dhi = (widx == 0) ? qkvb : (widx == 1) ? qkvb + 2 * (size_t)NQKV : qkvb + 4 * (size_t)NQKV;
    unsigned short* dlo = (widx == 2) ? (unsigned short*)0 : dhi + NQKV;
    const float scale = (widx == 0) ? 0.125f : 1.0f;   // D^-0.5

    f32x4 acc[4][4];
#pragma unroll
    for (int i = 0; i < 4; i++)
#pragma unroll
        for (int j = 0; j < 4; j++) acc[i][j] = (f32x4)0.f;

    mfma_gemm_body(hs_hi, hs_lo, Wh, Wl, mbase, nbase, acc);

    const int lane = threadIdx.x & 63;
    const int w    = threadIdx.x >> 6;
    const int quad = lane >> 4, l16 = lane & 15;
    const int wm = (w >> 1) * 64, wn = (w & 1) * 64;
#pragma unroll
    for (int j = 0; j < 4; j++) {
        int n = nbase + wn + j * 16 + l16;
        int h = n >> 6, d = n & 63;
        float bj = bias[n];
#pragma unroll
        for (int i = 0; i < 4; i++) {
#pragma unroll
            for (int rr = 0; rr < 4; rr++) {
                int m = mbase + wm + i * 16 + quad * 4 + rr;
                int b = m >> 10, t = m & 1023;
                float val = (acc[i][j][rr] + bj) * scale;
                unsigned short hi, lo;
                split_bf(val, hi, lo);
                size_t off = (((size_t)(b * HH + h) * TT + t) * DD + d);
                dhi[off] = hi;
                if (dlo) dlo[off] = lo;
            }
        }
    }
}

// ---------------------------------------------------------------------------
// Out projection (MFMA): out = ctx @ Wo^T + bo, fp32 out.
// ---------------------------------------------------------------------------
__global__ __launch_bounds__(256)
void outproj_kernel(const unsigned short* __restrict__ ws_ro,
                    const float* __restrict__ bo, float* __restrict__ out)
{
    const int nbase = blockIdx.x * 128;
    const int mbase = blockIdx.y * 128;
    const unsigned short* ctx_hi = ws_ro;            // aliases hs planes
    const unsigned short* ctx_lo = ws_ro + N_HS;
    const unsigned short* Wh = ws_ro + 2 * (size_t)N_HS + 3 * 2 * (size_t)N_W;  // Wo
    const unsigned short* Wl = Wh + N_W;

    f32x4 acc[4][4];
#pragma unroll
    for (int i = 0; i < 4; i++)
#pragma unroll
        for (int j = 0; j < 4; j++) acc[i][j] = (f32x4)0.f;

    mfma_gemm_body(ctx_hi, ctx_lo, Wh, Wl, mbase, nbase, acc);

    const int lane = threadIdx.x & 63;
    const int w    = threadIdx.x >> 6;
    const int quad = lane >> 4, l16 = lane & 15;
    const int wm = (w >> 1) * 64, wn = (w & 1) * 64;
#pragma unroll
    for (int j = 0; j < 4; j++) {
        int n = nbase + wn + j * 16 + l16;
        float bj = bo[n];
#pragma unroll
        for (int i = 0; i < 4; i++) {
#pragma unroll
            for (int rr = 0; rr < 4; rr++) {
                int m = mbase + wm + i * 16 + quad * 4 + rr;
                out[(size_t)m * EE + n] = acc[i][j][rr] + bj;
            }
        }
    }
}

// ---------------------------------------------------------------------------
// MFMA flash attention (unchanged from R2 except: epilogue writes ctx as
// bf16 hi/lo planes for the MFMA out-projection).
// ---------------------------------------------------------------------------
#define LS 72   // LDS row stride in ushorts

__global__ __launch_bounds__(256)
void attn_kernel(const unsigned short* __restrict__ qh_, const unsigned short* __restrict__ ql_,
                 const unsigned short* __restrict__ kh_, const unsigned short* __restrict__ kl_,
                 const unsigned short* __restrict__ vh_,
                 const float* __restrict__ mask,
                 unsigned short* __restrict__ ctxh, unsigned short* __restrict__ ctxl)
{
    __shared__ unsigned short Ksh[64 * LS];
    __shared__ unsigned short Ksl[64 * LS];
    __shared__ unsigned short Vt [64 * LS];
    __shared__ unsigned short Ps [64 * LS];

    const int bh = blockIdx.y;
    const int b  = bh >> 4;
    const int h  = bh & 15;
    const int m0 = blockIdx.x * 64;
    const size_t hoff = (size_t)bh * TT * DD;
    const unsigned short* qhp = qh_ + hoff;
    const unsigned short* qlp = ql_ + hoff;
    const unsigned short* khp = kh_ + hoff;
    const unsigned short* klp = kl_ + hoff;
    const unsigned short* vhp = vh_ + hoff;
    const float* mb = mask + (size_t)b * TT * TT;

    const int tid  = threadIdx.x;
    const int w    = tid >> 6;
    const int lane = tid & 63;
    const int quad = lane >> 4;
    const int l16  = lane & 15;

    bf16x8 qfh[2], qfl[2];
#pragma unroll
    for (int s = 0; s < 2; s++) {
        size_t off = (size_t)(m0 + w * 16 + l16) * DD + s * 32 + quad * 8;
        qfh[s] = *(const bf16x8*)(qhp + off);
        qfl[s] = *(const bf16x8*)(qlp + off);
    }

    f32x4 o[4];
    float m_i[4], l_i[4];
#pragma unroll
    for (int t = 0; t < 4; t++) o[t] = (f32x4)0.f;
#pragma unroll
    for (int r = 0; r < 4; r++) { m_i[r] = -INFINITY; l_i[r] = 0.f; }

    for (int n0 = 0; n0 < TT; n0 += 64) {
        float mreg[4][4];
#pragma unroll
        for (int t = 0; t < 4; t++)
#pragma unroll
            for (int r = 0; r < 4; r++)
                mreg[t][r] = mb[(size_t)(m0 + w * 16 + quad * 4 + r) * TT + n0 + 16 * t + l16];

        __syncthreads();
#pragma unroll
        for (int i = 0; i < 2; i++) {
            int u = tid + i * 256;
            int r = u >> 3, c8 = (u & 7) * 8;
            *(uint4*)&Ksh[r * LS + c8] = *(const uint4*)(khp + (size_t)(n0 + r) * DD + c8);
            *(uint4*)&Ksl[r * LS + c8] = *(const uint4*)(klp + (size_t)(n0 + r) * DD + c8);
        }
        {
            int n  = tid & 63;
            int d0 = (tid >> 6) * 8;
#pragma unroll
            for (int half = 0; half < 2; half++) {
                int dd = d0 + half * 32;
                uint4 rv = *(const uint4*)(vhp + (size_t)(n0 + n) * DD + dd);
                unsigned int uu[4] = {rv.x, rv.y, rv.z, rv.w};
#pragma unroll
                for (int j = 0; j < 4; j++) {
                    Vt[(dd + 2 * j + 0) * LS + n] = (unsigned short)(uu[j] & 0xFFFFu);
                    Vt[(dd + 2 * j + 1) * LS + n] = (unsigned short)(uu[j] >> 16);
                }
            }
        }
        __syncthreads();

        f32x4 st[4];
#pragma unroll
        for (int t = 0; t < 4; t++) {
            f32x4 sv;
            sv[0] = mreg[t][0]; sv[1] = mreg[t][1]; sv[2] = mreg[t][2]; sv[3] = mreg[t][3];
            st[t] = sv;
        }
#pragma unroll
        for (int s = 0; s < 2; s++) {
#pragma unroll
            for (int t = 0; t < 4; t++) {
                const bf16x8 kh = *(const bf16x8*)&Ksh[(16 * t + l16) * LS + s * 32 + quad * 8];
                const bf16x8 kl = *(const bf16x8*)&Ksl[(16 * t + l16) * LS + s * 32 + quad * 8];
                st[t] = __builtin_amdgcn_mfma_f32_16x16x32_bf16(qfh[s], kh, st[t], 0, 0, 0);
                st[t] = __builtin_amdgcn_mfma_f32_16x16x32_bf16(qfh[s], kl, st[t], 0, 0, 0);
                st[t] = __builtin_amdgcn_mfma_f32_16x16x32_bf16(qfl[s], kh, st[t], 0, 0, 0);
            }
        }

        float rm[4], rs[4], alpha[4];
#pragma unroll
        for (int r = 0; r < 4; r++)
            rm[r] = fmaxf(fmaxf(st[0][r], st[1][r]), fmaxf(st[2][r], st[3][r]));
#pragma unroll
        for (int mky = 1; mky < 16; mky <<= 1)
#pragma unroll
            for (int r = 0; r < 4; r++)
                rm[r] = fmaxf(rm[r], __shfl_xor(rm[r], mky));
#pragma unroll
        for (int r = 0; r < 4; r++) {
            float mn = fmaxf(m_i[r], rm[r]);
            alpha[r] = __expf(m_i[r] - mn);
            m_i[r]   = mn;
            rs[r]    = 0.f;
        }
#pragma unroll
        for (int t = 0; t < 4; t++)
#pragma unroll
            for (int r = 0; r < 4; r++) {
                float p = __expf(st[t][r] - m_i[r]);
                st[t][r] = p;
                rs[r] += p;
            }
#pragma unroll
        for (int mky = 1; mky < 16; mky <<= 1)
#pragma unroll
            for (int r = 0; r < 4; r++)
                rs[r] += __shfl_xor(rs[r], mky);
#pragma unroll
        for (int r = 0; r < 4; r++)
            l_i[r] = l_i[r] * alpha[r] + rs[r];
#pragma unroll
        for (int t = 0; t < 4; t++)
#pragma unroll
            for (int r = 0; r < 4; r++)
                o[t][r] *= alpha[r];

#pragma unroll
        for (int t = 0; t < 4; t++)
#pragma unroll
            for (int r = 0; r < 4; r++)
                Ps[(w * 16 + quad * 4 + r) * LS + 16 * t + l16] = f2bf(st[t][r]);

#pragma unroll
        for (int s = 0; s < 2; s++) {
            const bf16x8 pf = *(const bf16x8*)&Ps[(w * 16 + l16) * LS + s * 32 + quad * 8];
#pragma unroll
            for (int t = 0; t < 4; t++) {
                const bf16x8 vf = *(const bf16x8*)&Vt[(16 * t + l16) * LS + s * 32 + quad * 8];
                o[t] = __builtin_amdgcn_mfma_f32_16x16x32_bf16(pf, vf, o[t], 0, 0, 0);
            }
        }
    }

    // epilogue: normalize, split to bf16 hi/lo ctx planes [B,T,E]
#pragma unroll
    for (int r = 0; r < 4; r++) {
        float inv = 1.0f / l_i[r];
        int m = m0 + w * 16 + quad * 4 + r;
#pragma unroll
        for (int t = 0; t < 4; t++) {
            float val = o[t][r] * inv;
            unsigned short hi, lo;
            split_bf(val, hi, lo);
            size_t off = (size_t)(b * TT + m) * EE + h * DD + 16 * t + l16;
            ctxh[off] = hi;
            ctxl[off] = lo;
        }
    }
}

// ---------------------------------------------------------------------------
extern "C" void kernel_launch(void* const* d_in, const int* in_sizes, int n_in,
                              void* d_out, int out_size, void* d_ws, size_t ws_size,
                              hipStream_t stream)
{
    const float* hs   = (const float*)d_in[0];
    const float* mask = (const float*)d_in[1];
    const float* Wq   = (const float*)d_in[2];
    const float* bq   = (const float*)d_in[3];
    const float* Wk   = (const float*)d_in[4];
    const float* bk   = (const float*)d_in[5];
    const float* Wv   = (const float*)d_in[6];
    const float* bv   = (const float*)d_in[7];
    const float* Wo   = (const float*)d_in[8];
    const float* bo   = (const float*)d_in[9];
    float* out = (float*)d_out;

    unsigned short* ws = (unsigned short*)d_ws;
    unsigned short* qkvb = ws + 2 * (size_t)N_HS + 8 * (size_t)N_W;
    unsigned short* qhi = qkvb;
    unsigned short* qlo = qhi + NQKV;
    unsigned short* khi = qlo + NQKV;
    unsigned short* klo = khi + NQKV;
    unsigned short* vhi = klo + NQKV;
    unsigned short* ctxh = ws;            // alias hs planes (hs dead after qkv)
    unsigned short* ctxl = ws + N_HS;

    split_kernel<<<8192, 256, 0, stream>>>(hs, Wq, Wk, Wv, Wo, ws);
    qkv_kernel<<<dim3(24, 32), 256, 0, stream>>>(ws, bq, bk, bv, ws);
    attn_kernel<<<dim3(TT / 64, BB * HH), 256, 0, stream>>>(qhi, qlo, khi, klo, vhi, mask, ctxh, ctxl);
    outproj_kernel<<<dim3(8, 32), 256, 0, stream>>>(ws, bo, out);
}

// Round 4
// 230.596 us; speedup vs baseline: 3.8499x; 1.4175x over previous
//
#include <hip/hip_runtime.h>
#include <math.h>

// Problem constants
#define BB 4
#define TT 1024
#define EE 1024
#define HH 16
#define DD 64
#define KDIM 1024
#define N_HS (4096 * 1024)     // hidden_states elems (also ctx)
#define N_W  (1024 * 1024)     // one weight matrix elems
#define NQKV (BB * HH * TT * DD)

typedef _Float16 f16x8 __attribute__((ext_vector_type(8)));   // 4 VGPRs
typedef float    f32x4 __attribute__((ext_vector_type(4)));

// fp32 -> fp16 bits, RTNE (v_cvt_f16_f32 under default round mode)
__device__ __forceinline__ unsigned short f2h(float x) {
    _Float16 h = (_Float16)x;
    return __builtin_bit_cast(unsigned short, h);
}
// split x = hi + lo, both fp16
__device__ __forceinline__ void split_h(float x, unsigned short& hi, unsigned short& lo) {
    _Float16 h = (_Float16)x;
    hi = __builtin_bit_cast(unsigned short, h);
    lo = f2h(x - (float)h);
}

// async global->LDS 16B copy
__device__ __forceinline__ void gload16(const void* g, void* l) {
    __builtin_amdgcn_global_load_lds(
        (const __attribute__((address_space(1))) void*)g,
        (__attribute__((address_space(3))) void*)l, 16, 0, 0);
}

// ---------------------------------------------------------------------------
// Elementwise fp32 -> fp16 convert: hs + 4 weights, single plane each.
// ws layout (ushort units):
//   [0]                      hs (N_HS)            (aliased as ctx_hi later)
//   [N_HS]                   wq, wk, wv, wo       (N_W each)
//   [N_HS+4*N_W]             q, k, v              (NQKV each)
//   [N_HS+4*N_W+3*NQKV]      ctx_lo               (N_HS)
// ---------------------------------------------------------------------------
__global__ __launch_bounds__(256)
void split_kernel(const float* __restrict__ hs,
                  const float* __restrict__ Wq, const float* __restrict__ Wk,
                  const float* __restrict__ Wv, const float* __restrict__ Wo,
                  unsigned short* __restrict__ ws)
{
    const int u = blockIdx.x * 256 + threadIdx.x;   // float4 id, 2,097,152 total
    const float* src;
    unsigned short* dst;
    if (u < (N_HS / 4)) {
        src = hs + (size_t)u * 4;
        dst = ws + (size_t)u * 4;
    } else {
        int v = u - N_HS / 4;
        int wsel = v >> 18;             // N_W/4 = 262144 float4 per weight
        int wo   = v & 0x3FFFF;
        const float* Wsrc = (wsel == 0) ? Wq : (wsel == 1) ? Wk : (wsel == 2) ? Wv : Wo;
        src = Wsrc + (size_t)wo * 4;
        dst = ws + (size_t)N_HS + (size_t)wsel * N_W + (size_t)wo * 4;
    }
    float4 x = *(const float4*)src;
    ushort4 h4;
    h4.x = f2h(x.x); h4.y = f2h(x.y); h4.z = f2h(x.z); h4.w = f2h(x.w);
    *(ushort4*)dst = h4;
}

// ---------------------------------------------------------------------------
// QKV projection, single-fp16 MFMA. C = A @ W^T, 128x128 tile, BK=32,
// 4 waves (2x2 of 64x64), 16x16x32_f16. global_load_lds width-16 with
// source-side K-chunk XOR swizzle (slot = r*4 + (c ^ ((r>>1)&3))) ->
// frag ds_read_b128 2-way banked (free). LDS = 16 KB.
// grid.x = 24: widx = x>>3 selects q/k/v; grid.y = 32 m-tiles.
// ---------------------------------------------------------------------------
__global__ __launch_bounds__(256)
void qkv_kernel(const unsigned short* __restrict__ hsp,
                const unsigned short* __restrict__ wqp,
                const float* __restrict__ bq, const float* __restrict__ bk,
                const float* __restrict__ bv,
                unsigned short* __restrict__ qkvb)
{
    __shared__ unsigned short Ah[128 * 32], Bh[128 * 32];

    const int widx  = blockIdx.x >> 3;
    const int nbase = (blockIdx.x & 7) * 128;
    const int mbase = blockIdx.y * 128;
    const unsigned short* Wp = wqp + (size_t)widx * N_W;
    const float* bias = (widx == 0) ? bq : (widx == 1) ? bk : bv;
    unsigned short* dst = qkvb + (size_t)widx * NQKV;
    const float scale = (widx == 0) ? 0.125f : 1.0f;   // D^-0.5

    const int tid  = threadIdx.x;
    const int w    = tid >> 6;
    const int lane = tid & 63;
    const int quad = lane >> 4;
    const int l16  = lane & 15;
    const int wm   = (w >> 1) * 64;
    const int wn   = (w & 1) * 64;

    f32x4 acc[4][4];
#pragma unroll
    for (int i = 0; i < 4; i++)
#pragma unroll
        for (int j = 0; j < 4; j++) acc[i][j] = (f32x4)0.f;

#pragma unroll 1
    for (int kt = 0; kt < KDIM; kt += 32) {
        __syncthreads();
#pragma unroll
        for (int i = 0; i < 2; i++) {
            int u = tid + i * 256;              // 16B chunk id, 512/plane
            int r = u >> 2, c = u & 3;
            int q = c ^ ((r >> 1) & 3);
            gload16(hsp + (size_t)(mbase + r) * KDIM + kt + q * 8, &Ah[u * 8]);
            gload16(Wp  + (size_t)(nbase + r) * KDIM + kt + q * 8, &Bh[u * 8]);
        }
        __syncthreads();

        f16x8 af[4], bfr[4];
#pragma unroll
        for (int i = 0; i < 4; i++) {
            int r = wm + i * 16 + l16;
            af[i] = *(const f16x8*)&Ah[(r * 4 + (quad ^ ((r >> 1) & 3))) * 8];
        }
#pragma unroll
        for (int j = 0; j < 4; j++) {
            int r = wn + j * 16 + l16;
            bfr[j] = *(const f16x8*)&Bh[(r * 4 + (quad ^ ((r >> 1) & 3))) * 8];
        }
#pragma unroll
        for (int i = 0; i < 4; i++)
#pragma unroll
            for (int j = 0; j < 4; j++)
                acc[i][j] = __builtin_amdgcn_mfma_f32_16x16x32_f16(af[i], bfr[j], acc[i][j], 0, 0, 0);
    }

    // epilogue: +bias, *scale, fp16, scatter to [B,H,T,D]
#pragma unroll
    for (int j = 0; j < 4; j++) {
        int n = nbase + wn + j * 16 + l16;
        int h = n >> 6, d = n & 63;
        float bj = bias[n];
#pragma unroll
        for (int i = 0; i < 4; i++)
#pragma unroll
            for (int rr = 0; rr < 4; rr++) {
                int m = mbase + wm + i * 16 + quad * 4 + rr;
                int b = m >> 10, t = m & 1023;
                dst[(((size_t)(b * HH + h) * TT + t) * DD + d)] =
                    f2h((acc[i][j][rr] + bj) * scale);
            }
    }
}

// ---------------------------------------------------------------------------
// Out projection, 2-term fp16: out = (ctx_hi + ctx_lo) @ Wo^T + bo.
// Tile 64m x 128n, BK=32, grid 8x64 = 512 blocks (2/CU). LDS 16 KB.
// ---------------------------------------------------------------------------
__global__ __launch_bounds__(256)
void outproj_kernel(const unsigned short* __restrict__ ctxh,
                    const unsigned short* __restrict__ ctxl,
                    const unsigned short* __restrict__ wop,
                    const float* __restrict__ bo, float* __restrict__ out)
{
    __shared__ unsigned short Ach[64 * 32], Acl[64 * 32], Bh[128 * 32];

    const int nbase = blockIdx.x * 128;
    const int mbase = blockIdx.y * 64;

    const int tid  = threadIdx.x;
    const int w    = tid >> 6;
    const int lane = tid & 63;
    const int quad = lane >> 4;
    const int l16  = lane & 15;
    const int wm   = (w >> 1) * 32;
    const int wn   = (w & 1) * 64;

    f32x4 acc[2][4];
#pragma unroll
    for (int i = 0; i < 2; i++)
#pragma unroll
        for (int j = 0; j < 4; j++) acc[i][j] = (f32x4)0.f;

#pragma unroll 1
    for (int kt = 0; kt < KDIM; kt += 32) {
        __syncthreads();
        {
            // A planes: 256 chunks each (64 rows x 4), 1 chunk/thread/plane
            int r = tid >> 2, c = tid & 3;
            int q = c ^ ((r >> 1) & 3);
            size_t ga = (size_t)(mbase + r) * KDIM + kt + q * 8;
            gload16(ctxh + ga, &Ach[tid * 8]);
            gload16(ctxl + ga, &Acl[tid * 8]);
        }
#pragma unroll
        for (int i = 0; i < 2; i++) {
            int u = tid + i * 256;              // B: 512 chunks (128 rows x 4)
            int r = u >> 2, c = u & 3;
            int q = c ^ ((r >> 1) & 3);
            gload16(wop + (size_t)(nbase + r) * KDIM + kt + q * 8, &Bh[u * 8]);
        }
        __syncthreads();

        f16x8 ah[2], al[2], bfr[4];
#pragma unroll
        for (int i = 0; i < 2; i++) {
            int r = wm + i * 16 + l16;
            int slot = (r * 4 + (quad ^ ((r >> 1) & 3))) * 8;
            ah[i] = *(const f16x8*)&Ach[slot];
            al[i] = *(const f16x8*)&Acl[slot];
        }
#pragma unroll
        for (int j = 0; j < 4; j++) {
            int r = wn + j * 16 + l16;
            bfr[j] = *(const f16x8*)&Bh[(r * 4 + (quad ^ ((r >> 1) & 3))) * 8];
        }
#pragma unroll
        for (int i = 0; i < 2; i++)
#pragma unroll
            for (int j = 0; j < 4; j++) {
                acc[i][j] = __builtin_amdgcn_mfma_f32_16x16x32_f16(ah[i], bfr[j], acc[i][j], 0, 0, 0);
                acc[i][j] = __builtin_amdgcn_mfma_f32_16x16x32_f16(al[i], bfr[j], acc[i][j], 0, 0, 0);
            }
    }

#pragma unroll
    for (int j = 0; j < 4; j++) {
        int n = nbase + wn + j * 16 + l16;
        float bj = bo[n];
#pragma unroll
        for (int i = 0; i < 2; i++)
#pragma unroll
            for (int rr = 0; rr < 4; rr++) {
                int m = mbase + wm + i * 16 + quad * 4 + rr;
                out[(size_t)m * EE + n] = acc[i][j][rr] + bj;
            }
    }
}

// ---------------------------------------------------------------------------
// MFMA flash attention, fp16. BM=64 (16 q-rows/wave), BN=64, D=64.
// QK^T: 1 MFMA per (s,t); K staged via global_load_lds with source-side
// XOR swizzle into unpadded Ks (2-way banked frag reads). V transposed via
// VGPR into padded Vt. P fp16 -> per-wave LDS strip -> A-frag. LDS 26.5 KB.
// Epilogue writes ctx as fp16 hi/lo planes for the 2-term out projection.
// ---------------------------------------------------------------------------
#define LS 72   // padded row stride (ushorts) for Vt/Ps

__global__ __launch_bounds__(256)
void attn_kernel(const unsigned short* __restrict__ qp_, const unsigned short* __restrict__ kp_,
                 const unsigned short* __restrict__ vp_,
                 const float* __restrict__ mask,
                 unsigned short* __restrict__ ctxh, unsigned short* __restrict__ ctxl)
{
    __shared__ unsigned short Ks[64 * 64];     // swizzled, unpadded
    __shared__ unsigned short Vt[64 * LS];
    __shared__ unsigned short Ps[64 * LS];

    const int bh = blockIdx.y;
    const int b  = bh >> 4;
    const int h  = bh & 15;
    const int m0 = blockIdx.x * 64;
    const size_t hoff = (size_t)bh * TT * DD;
    const unsigned short* qhp = qp_ + hoff;
    const unsigned short* khp = kp_ + hoff;
    const unsigned short* vhp = vp_ + hoff;
    const float* mb = mask + (size_t)b * TT * TT;

    const int tid  = threadIdx.x;
    const int w    = tid >> 6;
    const int lane = tid & 63;
    const int quad = lane >> 4;
    const int l16  = lane & 15;

    // Q fragments, resident whole kernel (A-frag: m=l16, k=s*32+quad*8+j)
    f16x8 qf[2];
#pragma unroll
    for (int s = 0; s < 2; s++)
        qf[s] = *(const f16x8*)(qhp + (size_t)(m0 + w * 16 + l16) * DD + s * 32 + quad * 8);

    f32x4 o[4];
    float m_i[4], l_i[4];
#pragma unroll
    for (int t = 0; t < 4; t++) o[t] = (f32x4)0.f;
#pragma unroll
    for (int r = 0; r < 4; r++) { m_i[r] = -INFINITY; l_i[r] = 0.f; }

    for (int n0 = 0; n0 < TT; n0 += 64) {
        // mask values (row m0+w*16+quad*4+r, col n0+16t+l16)
        float mreg[4][4];
#pragma unroll
        for (int t = 0; t < 4; t++)
#pragma unroll
            for (int r = 0; r < 4; r++)
                mreg[t][r] = mb[(size_t)(m0 + w * 16 + quad * 4 + r) * TT + n0 + 16 * t + l16];

        __syncthreads();   // previous iteration's readers done with Ks/Vt
        // K stage: 512 16B chunks, linear LDS dest, swizzled global source
#pragma unroll
        for (int i = 0; i < 2; i++) {
            int u = tid + i * 256;
            int r = u >> 3, cp = u & 7;
            int c = cp ^ (r & 7);
            gload16(khp + (size_t)(n0 + r) * DD + c * 8, &Ks[u * 8]);
        }
        // V transpose: lane n-fast scatter into padded Vt
        {
            int n  = tid & 63;
            int d0 = (tid >> 6) * 8;
#pragma unroll
            for (int half = 0; half < 2; half++) {
                int dd = d0 + half * 32;
                uint4 rv = *(const uint4*)(vhp + (size_t)(n0 + n) * DD + dd);
                unsigned int uu[4] = {rv.x, rv.y, rv.z, rv.w};
#pragma unroll
                for (int j = 0; j < 4; j++) {
                    Vt[(dd + 2 * j + 0) * LS + n] = (unsigned short)(uu[j] & 0xFFFFu);
                    Vt[(dd + 2 * j + 1) * LS + n] = (unsigned short)(uu[j] >> 16);
                }
            }
        }
        __syncthreads();

        // S = Q.K^T + mask
        f32x4 st[4];
#pragma unroll
        for (int t = 0; t < 4; t++) {
            f32x4 sv;
            sv[0] = mreg[t][0]; sv[1] = mreg[t][1]; sv[2] = mreg[t][2]; sv[3] = mreg[t][3];
            st[t] = sv;
        }
#pragma unroll
        for (int s = 0; s < 2; s++)
#pragma unroll
            for (int t = 0; t < 4; t++) {
                int R = 16 * t + l16;
                const f16x8 kf = *(const f16x8*)&Ks[(R * 8 + ((s * 4 + quad) ^ (R & 7))) * 8];
                st[t] = __builtin_amdgcn_mfma_f32_16x16x32_f16(qf[s], kf, st[t], 0, 0, 0);
            }

        // online softmax (fp32)
        float rm[4], rs[4], alpha[4];
#pragma unroll
        for (int r = 0; r < 4; r++)
            rm[r] = fmaxf(fmaxf(st[0][r], st[1][r]), fmaxf(st[2][r], st[3][r]));
#pragma unroll
        for (int mky = 1; mky < 16; mky <<= 1)
#pragma unroll
            for (int r = 0; r < 4; r++)
                rm[r] = fmaxf(rm[r], __shfl_xor(rm[r], mky));
#pragma unroll
        for (int r = 0; r < 4; r++) {
            float mn = fmaxf(m_i[r], rm[r]);
            alpha[r] = __expf(m_i[r] - mn);
            m_i[r]   = mn;
            rs[r]    = 0.f;
        }
#pragma unroll
        for (int t = 0; t < 4; t++)
#pragma unroll
            for (int r = 0; r < 4; r++) {
                float p = __expf(st[t][r] - m_i[r]);
                st[t][r] = p;
                rs[r] += p;
            }
#pragma unroll
        for (int mky = 1; mky < 16; mky <<= 1)
#pragma unroll
            for (int r = 0; r < 4; r++)
                rs[r] += __shfl_xor(rs[r], mky);
#pragma unroll
        for (int r = 0; r < 4; r++)
            l_i[r] = l_i[r] * alpha[r] + rs[r];
#pragma unroll
        for (int t = 0; t < 4; t++)
#pragma unroll
            for (int r = 0; r < 4; r++)
                o[t][r] *= alpha[r];

        // P (C-layout) -> fp16 LDS, per-wave private strip; same-wave RAW is
        // in-order via lgkmcnt, no barrier needed.
#pragma unroll
        for (int t = 0; t < 4; t++)
#pragma unroll
            for (int r = 0; r < 4; r++)
                Ps[(w * 16 + quad * 4 + r) * LS + 16 * t + l16] = f2h(st[t][r]);

        // O += P.V
#pragma unroll
        for (int s = 0; s < 2; s++) {
            const f16x8 pf = *(const f16x8*)&Ps[(w * 16 + l16) * LS + s * 32 + quad * 8];
#pragma unroll
            for (int t = 0; t < 4; t++) {
                const f16x8 vf = *(const f16x8*)&Vt[(16 * t + l16) * LS + s * 32 + quad * 8];
                o[t] = __builtin_amdgcn_mfma_f32_16x16x32_f16(pf, vf, o[t], 0, 0, 0);
            }
        }
    }

    // epilogue: normalize, split fp16 hi/lo ctx planes [B,T,E]
#pragma unroll
    for (int r = 0; r < 4; r++) {
        float inv = 1.0f / l_i[r];
        int m = m0 + w * 16 + quad * 4 + r;
#pragma unroll
        for (int t = 0; t < 4; t++) {
            float val = o[t][r] * inv;
            unsigned short hi, lo;
            split_h(val, hi, lo);
            size_t off = (size_t)(b * TT + m) * EE + h * DD + 16 * t + l16;
            ctxh[off] = hi;
            ctxl[off] = lo;
        }
    }
}

// ---------------------------------------------------------------------------
extern "C" void kernel_launch(void* const* d_in, const int* in_sizes, int n_in,
                              void* d_out, int out_size, void* d_ws, size_t ws_size,
                              hipStream_t stream)
{
    const float* hs   = (const float*)d_in[0];
    const float* mask = (const float*)d_in[1];
    const float* Wq   = (const float*)d_in[2];
    const float* bq   = (const float*)d_in[3];
    const float* Wk   = (const float*)d_in[4];
    const float* bk   = (const float*)d_in[5];
    const float* Wv   = (const float*)d_in[6];
    const float* bv   = (const float*)d_in[7];
    const float* Wo   = (const float*)d_in[8];
    const float* bo   = (const float*)d_in[9];
    float* out = (float*)d_out;

    unsigned short* ws   = (unsigned short*)d_ws;
    unsigned short* hsp  = ws;                                  // fp16 hs (-> ctx_hi)
    unsigned short* wqp  = ws + (size_t)N_HS;                   // wq,wk,wv,wo
    unsigned short* wop  = wqp + 3 * (size_t)N_W;
    unsigned short* qkvb = wqp + 4 * (size_t)N_W;               // q,k,v planes
    unsigned short* qp   = qkvb;
    unsigned short* kp   = qp + (size_t)NQKV;
    unsigned short* vp   = kp + (size_t)NQKV;
    unsigned short* ctxh = ws;                                  // alias hs (dead after qkv)
    unsigned short* ctxl = qkvb + 3 * (size_t)NQKV;

    split_kernel<<<8192, 256, 0, stream>>>(hs, Wq, Wk, Wv, Wo, ws);
    qkv_kernel<<<dim3(24, 32), 256, 0, stream>>>(hsp, wqp, bq, bk, bv, qkvb);
    attn_kernel<<<dim3(TT / 64, BB * HH), 256, 0, stream>>>(qp, kp, vp, mask, ctxh, ctxl);
    outproj_kernel<<<dim3(8, 64), 256, 0, stream>>>(ctxh, ctxl, wop, bo, out);
}

// Round 5
// 228.777 us; speedup vs baseline: 3.8805x; 1.0079x over previous
//
#include <hip/hip_runtime.h>
#include <math.h>

// Problem constants
#define BB 4
#define TT 1024
#define EE 1024
#define HH 16
#define DD 64
#define KDIM 1024
#define N_HS (4096 * 1024)     // hidden_states elems (also ctx)
#define N_W  (1024 * 1024)     // one weight matrix elems
#define NQKV (BB * HH * TT * DD)

typedef _Float16 f16x8 __attribute__((ext_vector_type(8)));   // 4 VGPRs
typedef float    f32x4 __attribute__((ext_vector_type(4)));

// fp32 -> fp16 bits, RTNE
__device__ __forceinline__ unsigned short f2h(float x) {
    _Float16 h = (_Float16)x;
    return __builtin_bit_cast(unsigned short, h);
}
// split x = hi + lo, both fp16
__device__ __forceinline__ void split_h(float x, unsigned short& hi, unsigned short& lo) {
    _Float16 h = (_Float16)x;
    hi = __builtin_bit_cast(unsigned short, h);
    lo = f2h(x - (float)h);
}

// async global->LDS 16B copy
__device__ __forceinline__ void gload16(const void* g, void* l) {
    __builtin_amdgcn_global_load_lds(
        (const __attribute__((address_space(1))) void*)g,
        (__attribute__((address_space(3))) void*)l, 16, 0, 0);
}

// ---------------------------------------------------------------------------
// Elementwise fp32 -> fp16 convert: hs + 4 weights, single plane each.
// ws layout (ushort units):
//   [0]                      hs (N_HS)            (aliased as ctx_hi later)
//   [N_HS]                   wq, wk, wv, wo       (N_W each)
//   [N_HS+4*N_W]             q, k, v              (NQKV each)
//   [N_HS+4*N_W+3*NQKV]      ctx_lo               (N_HS)
//   [.. + N_HS]              vT                   (NQKV, [B,H,D,T])
// ---------------------------------------------------------------------------
__global__ __launch_bounds__(256)
void split_kernel(const float* __restrict__ hs,
                  const float* __restrict__ Wq, const float* __restrict__ Wk,
                  const float* __restrict__ Wv, const float* __restrict__ Wo,
                  unsigned short* __restrict__ ws)
{
    const int u = blockIdx.x * 256 + threadIdx.x;   // float4 id, 2,097,152 total
    const float* src;
    unsigned short* dst;
    if (u < (N_HS / 4)) {
        src = hs + (size_t)u * 4;
        dst = ws + (size_t)u * 4;
    } else {
        int v = u - N_HS / 4;
        int wsel = v >> 18;             // N_W/4 = 262144 float4 per weight
        int wo   = v & 0x3FFFF;
        const float* Wsrc = (wsel == 0) ? Wq : (wsel == 1) ? Wk : (wsel == 2) ? Wv : Wo;
        src = Wsrc + (size_t)wo * 4;
        dst = ws + (size_t)N_HS + (size_t)wsel * N_W + (size_t)wo * 4;
    }
    float4 x = *(const float4*)src;
    ushort4 h4;
    h4.x = f2h(x.x); h4.y = f2h(x.y); h4.z = f2h(x.z); h4.w = f2h(x.w);
    *(ushort4*)dst = h4;
}

// ---------------------------------------------------------------------------
// QKV projection, single-fp16 MFMA (unchanged from R4).
// ---------------------------------------------------------------------------
__global__ __launch_bounds__(256)
void qkv_kernel(const unsigned short* __restrict__ hsp,
                const unsigned short* __restrict__ wqp,
                const float* __restrict__ bq, const float* __restrict__ bk,
                const float* __restrict__ bv,
                unsigned short* __restrict__ qkvb)
{
    __shared__ unsigned short Ah[128 * 32], Bh[128 * 32];

    const int widx  = blockIdx.x >> 3;
    const int nbase = (blockIdx.x & 7) * 128;
    const int mbase = blockIdx.y * 128;
    const unsigned short* Wp = wqp + (size_t)widx * N_W;
    const float* bias = (widx == 0) ? bq : (widx == 1) ? bk : bv;
    unsigned short* dst = qkvb + (size_t)widx * NQKV;
    const float scale = (widx == 0) ? 0.125f : 1.0f;   // D^-0.5

    const int tid  = threadIdx.x;
    const int w    = tid >> 6;
    const int lane = tid & 63;
    const int quad = lane >> 4;
    const int l16  = lane & 15;
    const int wm   = (w >> 1) * 64;
    const int wn   = (w & 1) * 64;

    f32x4 acc[4][4];
#pragma unroll
    for (int i = 0; i < 4; i++)
#pragma unroll
        for (int j = 0; j < 4; j++) acc[i][j] = (f32x4)0.f;

#pragma unroll 1
    for (int kt = 0; kt < KDIM; kt += 32) {
        __syncthreads();
#pragma unroll
        for (int i = 0; i < 2; i++) {
            int u = tid + i * 256;              // 16B chunk id, 512/plane
            int r = u >> 2, c = u & 3;
            int q = c ^ ((r >> 1) & 3);
            gload16(hsp + (size_t)(mbase + r) * KDIM + kt + q * 8, &Ah[u * 8]);
            gload16(Wp  + (size_t)(nbase + r) * KDIM + kt + q * 8, &Bh[u * 8]);
        }
        __syncthreads();

        f16x8 af[4], bfr[4];
#pragma unroll
        for (int i = 0; i < 4; i++) {
            int r = wm + i * 16 + l16;
            af[i] = *(const f16x8*)&Ah[(r * 4 + (quad ^ ((r >> 1) & 3))) * 8];
        }
#pragma unroll
        for (int j = 0; j < 4; j++) {
            int r = wn + j * 16 + l16;
            bfr[j] = *(const f16x8*)&Bh[(r * 4 + (quad ^ ((r >> 1) & 3))) * 8];
        }
#pragma unroll
        for (int i = 0; i < 4; i++)
#pragma unroll
            for (int j = 0; j < 4; j++)
                acc[i][j] = __builtin_amdgcn_mfma_f32_16x16x32_f16(af[i], bfr[j], acc[i][j], 0, 0, 0);
    }

    // epilogue: +bias, *scale, fp16, scatter to [B,H,T,D]
#pragma unroll
    for (int j = 0; j < 4; j++) {
        int n = nbase + wn + j * 16 + l16;
        int h = n >> 6, d = n & 63;
        float bj = bias[n];
#pragma unroll
        for (int i = 0; i < 4; i++)
#pragma unroll
            for (int rr = 0; rr < 4; rr++) {
                int m = mbase + wm + i * 16 + quad * 4 + rr;
                int b = m >> 10, t = m & 1023;
                dst[(((size_t)(b * HH + h) * TT + t) * DD + d)] =
                    f2h((acc[i][j][rr] + bj) * scale);
            }
    }
}

// ---------------------------------------------------------------------------
// V transpose: [B,H,T,D] -> [B,H,D,T] fp16, via LDS tile. One block per
// (bh, 64-token tile). Global reads/writes both uint4-coalesced. The
// strided LDS gather has ~8-way conflicts but the kernel is ~4 us total.
// ---------------------------------------------------------------------------
__global__ __launch_bounds__(256)
void vtrans_kernel(const unsigned short* __restrict__ vp,
                   unsigned short* __restrict__ vtp)
{
    __shared__ unsigned short Ts[64 * 72];
    const int bh = blockIdx.y;
    const int t0 = blockIdx.x * 64;
    const unsigned short* src = vp  + (size_t)bh * TT * DD + (size_t)t0 * DD;
    unsigned short*       dst = vtp + (size_t)bh * DD * TT + t0;
    const int tid = threadIdx.x;

#pragma unroll
    for (int i = 0; i < 2; i++) {
        int id = tid + i * 256;           // 512 uint4: row r (token), chunk c (8 d)
        int r = id >> 3, c = id & 7;
        *(uint4*)&Ts[r * 72 + c * 8] = *(const uint4*)(src + (size_t)r * DD + c * 8);
    }
    __syncthreads();
#pragma unroll
    for (int i = 0; i < 2; i++) {
        int id = tid + i * 256;           // 512 uint4: row d, chunk c (8 tokens)
        int d = id >> 3, c = id & 7;
        unsigned short tmp[8];
#pragma unroll
        for (int j = 0; j < 8; j++) tmp[j] = Ts[(c * 8 + j) * 72 + d];
        uint4 o;
        o.x = (unsigned int)tmp[0] | ((unsigned int)tmp[1] << 16);
        o.y = (unsigned int)tmp[2] | ((unsigned int)tmp[3] << 16);
        o.z = (unsigned int)tmp[4] | ((unsigned int)tmp[5] << 16);
        o.w = (unsigned int)tmp[6] | ((unsigned int)tmp[7] << 16);
        *(uint4*)(dst + (size_t)d * TT + c * 8) = o;
    }
}

// ---------------------------------------------------------------------------
// Out projection, 2-term fp16 (unchanged from R4).
// ---------------------------------------------------------------------------
__global__ __launch_bounds__(256)
void outproj_kernel(const unsigned short* __restrict__ ctxh,
                    const unsigned short* __restrict__ ctxl,
                    const unsigned short* __restrict__ wop,
                    const float* __restrict__ bo, float* __restrict__ out)
{
    __shared__ unsigned short Ach[64 * 32], Acl[64 * 32], Bh[128 * 32];

    const int nbase = blockIdx.x * 128;
    const int mbase = blockIdx.y * 64;

    const int tid  = threadIdx.x;
    const int w    = tid >> 6;
    const int lane = tid & 63;
    const int quad = lane >> 4;
    const int l16  = lane & 15;
    const int wm   = (w >> 1) * 32;
    const int wn   = (w & 1) * 64;

    f32x4 acc[2][4];
#pragma unroll
    for (int i = 0; i < 2; i++)
#pragma unroll
        for (int j = 0; j < 4; j++) acc[i][j] = (f32x4)0.f;

#pragma unroll 1
    for (int kt = 0; kt < KDIM; kt += 32) {
        __syncthreads();
        {
            int r = tid >> 2, c = tid & 3;
            int q = c ^ ((r >> 1) & 3);
            size_t ga = (size_t)(mbase + r) * KDIM + kt + q * 8;
            gload16(ctxh + ga, &Ach[tid * 8]);
            gload16(ctxl + ga, &Acl[tid * 8]);
        }
#pragma unroll
        for (int i = 0; i < 2; i++) {
            int u = tid + i * 256;
            int r = u >> 2, c = u & 3;
            int q = c ^ ((r >> 1) & 3);
            gload16(wop + (size_t)(nbase + r) * KDIM + kt + q * 8, &Bh[u * 8]);
        }
        __syncthreads();

        f16x8 ah[2], al[2], bfr[4];
#pragma unroll
        for (int i = 0; i < 2; i++) {
            int r = wm + i * 16 + l16;
            int slot = (r * 4 + (quad ^ ((r >> 1) & 3))) * 8;
            ah[i] = *(const f16x8*)&Ach[slot];
            al[i] = *(const f16x8*)&Acl[slot];
        }
#pragma unroll
        for (int j = 0; j < 4; j++) {
            int r = wn + j * 16 + l16;
            bfr[j] = *(const f16x8*)&Bh[(r * 4 + (quad ^ ((r >> 1) & 3))) * 8];
        }
#pragma unroll
        for (int i = 0; i < 2; i++)
#pragma unroll
            for (int j = 0; j < 4; j++) {
                acc[i][j] = __builtin_amdgcn_mfma_f32_16x16x32_f16(ah[i], bfr[j], acc[i][j], 0, 0, 0);
                acc[i][j] = __builtin_amdgcn_mfma_f32_16x16x32_f16(al[i], bfr[j], acc[i][j], 0, 0, 0);
            }
    }

#pragma unroll
    for (int j = 0; j < 4; j++) {
        int n = nbase + wn + j * 16 + l16;
        float bj = bo[n];
#pragma unroll
        for (int i = 0; i < 2; i++)
#pragma unroll
            for (int rr = 0; rr < 4; rr++) {
                int m = mbase + wm + i * 16 + quad * 4 + rr;
                out[(size_t)m * EE + n] = acc[i][j][rr] + bj;
            }
    }
}

// ---------------------------------------------------------------------------
// MFMA flash attention, fp16. BM=64, BN=64, D=64. K AND V^T both staged via
// global_load_lds w/ source-side XOR swizzle (zero VGPR staging, no LDS
// scatter). PV B-frag reads V^T tile directly. LDS 25.5 KB.
// ---------------------------------------------------------------------------
#define LS 72   // padded row stride (ushorts) for Ps only

__global__ __launch_bounds__(256)
void attn_kernel(const unsigned short* __restrict__ qp_, const unsigned short* __restrict__ kp_,
                 const unsigned short* __restrict__ vtp_,
                 const float* __restrict__ mask,
                 unsigned short* __restrict__ ctxh, unsigned short* __restrict__ ctxl)
{
    __shared__ unsigned short Ks[64 * 64];     // swizzled, unpadded
    __shared__ unsigned short Vt[64 * 64];     // V^T tile: rows d, cols kv; swizzled
    __shared__ unsigned short Ps[64 * LS];

    const int bh = blockIdx.y;
    const int b  = bh >> 4;
    const int h  = bh & 15;
    const int m0 = blockIdx.x * 64;
    const size_t hoff = (size_t)bh * TT * DD;
    const unsigned short* qhp = qp_ + hoff;
    const unsigned short* khp = kp_ + hoff;
    const unsigned short* vtp = vtp_ + hoff;   // [D][T] for this bh
    const float* mb = mask + (size_t)b * TT * TT;

    const int tid  = threadIdx.x;
    const int w    = tid >> 6;
    const int lane = tid & 63;
    const int quad = lane >> 4;
    const int l16  = lane & 15;

    // Q fragments, resident whole kernel (A-frag: m=l16, k=s*32+quad*8+j)
    f16x8 qf[2];
#pragma unroll
    for (int s = 0; s < 2; s++)
        qf[s] = *(const f16x8*)(qhp + (size_t)(m0 + w * 16 + l16) * DD + s * 32 + quad * 8);

    f32x4 o[4];
    float m_i[4], l_i[4];
#pragma unroll
    for (int t = 0; t < 4; t++) o[t] = (f32x4)0.f;
#pragma unroll
    for (int r = 0; r < 4; r++) { m_i[r] = -INFINITY; l_i[r] = 0.f; }

    for (int n0 = 0; n0 < TT; n0 += 64) {
        // prefetch mask straight into the S accumulator (C-layout)
        f32x4 st[4];
#pragma unroll
        for (int t = 0; t < 4; t++)
#pragma unroll
            for (int r = 0; r < 4; r++)
                st[t][r] = mb[(size_t)(m0 + w * 16 + quad * 4 + r) * TT + n0 + 16 * t + l16];

        __syncthreads();   // previous iteration's readers done with Ks/Vt
        // K tile (rows kv, cols d) and V^T tile (rows d, cols kv), both via
        // async DMA, source-side swizzle: phys chunk cp holds logical cp^(r&7)
#pragma unroll
        for (int i = 0; i < 2; i++) {
            int u = tid + i * 256;
            int r = u >> 3, cp = u & 7;
            int c = cp ^ (r & 7);
            gload16(khp + (size_t)(n0 + r) * DD + c * 8, &Ks[u * 8]);
            gload16(vtp + (size_t)r * TT + n0 + c * 8,   &Vt[u * 8]);
        }
        __syncthreads();

        // S = Q.K^T + mask
#pragma unroll
        for (int s = 0; s < 2; s++)
#pragma unroll
            for (int t = 0; t < 4; t++) {
                int R = 16 * t + l16;
                const f16x8 kf = *(const f16x8*)&Ks[(R * 8 + ((s * 4 + quad) ^ (R & 7))) * 8];
                st[t] = __builtin_amdgcn_mfma_f32_16x16x32_f16(qf[s], kf, st[t], 0, 0, 0);
            }

        // online softmax (fp32)
        float rm[4], rs[4], alpha[4];
#pragma unroll
        for (int r = 0; r < 4; r++)
            rm[r] = fmaxf(fmaxf(st[0][r], st[1][r]), fmaxf(st[2][r], st[3][r]));
#pragma unroll
        for (int mky = 1; mky < 16; mky <<= 1)
#pragma unroll
            for (int r = 0; r < 4; r++)
                rm[r] = fmaxf(rm[r], __shfl_xor(rm[r], mky));
#pragma unroll
        for (int r = 0; r < 4; r++) {
            float mn = fmaxf(m_i[r], rm[r]);
            alpha[r] = __expf(m_i[r] - mn);
            m_i[r]   = mn;
            rs[r]    = 0.f;
        }
#pragma unroll
        for (int t = 0; t < 4; t++)
#pragma unroll
            for (int r = 0; r < 4; r++) {
                float p = __expf(st[t][r] - m_i[r]);
                st[t][r] = p;
                rs[r] += p;
            }
#pragma unroll
        for (int mky = 1; mky < 16; mky <<= 1)
#pragma unroll
            for (int r = 0; r < 4; r++)
                rs[r] += __shfl_xor(rs[r], mky);
#pragma unroll
        for (int r = 0; r < 4; r++)
            l_i[r] = l_i[r] * alpha[r] + rs[r];
#pragma unroll
        for (int t = 0; t < 4; t++)
#pragma unroll
            for (int r = 0; r < 4; r++)
                o[t][r] *= alpha[r];

        // P (C-layout) -> fp16 LDS, per-wave private strip (same-wave RAW:
        // in-order via lgkmcnt, no barrier needed)
#pragma unroll
        for (int t = 0; t < 4; t++)
#pragma unroll
            for (int r = 0; r < 4; r++)
                Ps[(w * 16 + quad * 4 + r) * LS + 16 * t + l16] = f2h(st[t][r]);

        // O += P.V  (A-frag from Ps; B-frag = V^T rows d=16t+l16, kv chunk)
#pragma unroll
        for (int s = 0; s < 2; s++) {
            const f16x8 pf = *(const f16x8*)&Ps[(w * 16 + l16) * LS + s * 32 + quad * 8];
#pragma unroll
            for (int t = 0; t < 4; t++) {
                int R = 16 * t + l16;
                const f16x8 vf = *(const f16x8*)&Vt[(R * 8 + ((s * 4 + quad) ^ (R & 7))) * 8];
                o[t] = __builtin_amdgcn_mfma_f32_16x16x32_f16(pf, vf, o[t], 0, 0, 0);
            }
        }
    }

    // epilogue: normalize, split fp16 hi/lo ctx planes [B,T,E]
#pragma unroll
    for (int r = 0; r < 4; r++) {
        float inv = 1.0f / l_i[r];
        int m = m0 + w * 16 + quad * 4 + r;
#pragma unroll
        for (int t = 0; t < 4; t++) {
            float val = o[t][r] * inv;
            unsigned short hi, lo;
            split_h(val, hi, lo);
            size_t off = (size_t)(b * TT + m) * EE + h * DD + 16 * t + l16;
            ctxh[off] = hi;
            ctxl[off] = lo;
        }
    }
}

// ---------------------------------------------------------------------------
extern "C" void kernel_launch(void* const* d_in, const int* in_sizes, int n_in,
                              void* d_out, int out_size, void* d_ws, size_t ws_size,
                              hipStream_t stream)
{
    const float* hs   = (const float*)d_in[0];
    const float* mask = (const float*)d_in[1];
    const float* Wq   = (const float*)d_in[2];
    const float* bq   = (const float*)d_in[3];
    const float* Wk   = (const float*)d_in[4];
    const float* bk   = (const float*)d_in[5];
    const float* Wv   = (const float*)d_in[6];
    const float* bv   = (const float*)d_in[7];
    const float* Wo   = (const float*)d_in[8];
    const float* bo   = (const float*)d_in[9];
    float* out = (float*)d_out;

    unsigned short* ws   = (unsigned short*)d_ws;
    unsigned short* hsp  = ws;                                  // fp16 hs (-> ctx_hi)
    unsigned short* wqp  = ws + (size_t)N_HS;                   // wq,wk,wv,wo
    unsigned short* wop  = wqp + 3 * (size_t)N_W;
    unsigned short* qkvb = wqp + 4 * (size_t)N_W;               // q,k,v planes
    unsigned short* qp   = qkvb;
    unsigned short* kp   = qp + (size_t)NQKV;
    unsigned short* vp   = kp + (size_t)NQKV;
    unsigned short* ctxh = ws;                                  // alias hs (dead after qkv)
    unsigned short* ctxl = qkvb + 3 * (size_t)NQKV;
    unsigned short* vtp  = ctxl + (size_t)N_HS;                 // V^T [B,H,D,T]

    split_kernel<<<8192, 256, 0, stream>>>(hs, Wq, Wk, Wv, Wo, ws);
    qkv_kernel<<<dim3(24, 32), 256, 0, stream>>>(hsp, wqp, bq, bk, bv, qkvb);
    vtrans_kernel<<<dim3(TT / 64, BB * HH), 256, 0, stream>>>(vp, vtp);
    attn_kernel<<<dim3(TT / 64, BB * HH), 256, 0, stream>>>(qp, kp, vtp, mask, ctxh, ctxl);
    outproj_kernel<<<dim3(8, 64), 256, 0, stream>>>(ctxh, ctxl, wop, bo, out);
}